// Round 7
// baseline (478.962 us; speedup 1.0000x reference)
//
#include <hip/hip_runtime.h>
#include <hip/hip_bf16.h>

#define N_NODES 100000
#define N_EDGES 1250000
#define D_FEAT  64

// ---- pass 1: coarse buckets of 1024 nodes ----
#define BKW       1024                           // nodes per coarse bucket
#define NB1       98                             // ceil(N_NODES / BKW)
#define SCAP      44                             // LDS staging entries per bucket (lambda=21)
#define CHUNK     2048                           // edges per block, pass 1
#define P1T       256
#define BCAP1     13440                          // mean 12800, +5.7 sigma
#define SPILL_CAP 65536

// record = (src << 10) | (dst & 1023)   (src < 2^17 -> 27 bits)
__global__ __launch_bounds__(P1T)
void k_bin(const int* __restrict__ src, const int* __restrict__ dst,
           int* __restrict__ bucket_cnt, unsigned* __restrict__ buckets,
           int* __restrict__ spill_cnt, int* __restrict__ spill) {
    __shared__ int      stg_cnt[NB1];            // 392 B
    __shared__ unsigned stg[NB1][SCAP];          // 17.2 KB
    int tid = threadIdx.x;
    for (int i = tid; i < NB1; i += P1T) stg_cnt[i] = 0;
    __syncthreads();

    int base = blockIdx.x * CHUNK;
    #pragma unroll
    for (int r = 0; r < CHUNK / P1T; ++r) {
        int e = base + r * P1T + tid;
        if (e < N_EDGES) {
            int d = dst[e], s = src[e];
            int b = d >> 10;
            int pos = atomicAdd(&stg_cnt[b], 1);
            unsigned rec = ((unsigned)s << 10) | (unsigned)(d & (BKW - 1));
            if (pos < SCAP) {
                stg[b][pos] = rec;
            } else {                               // staging overflow (very rare)
                int sp = atomicAdd(spill_cnt, 1);
                if (sp < SPILL_CAP) { spill[2 * sp] = d; spill[2 * sp + 1] = s; }
            }
        }
    }
    __syncthreads();

    // wave-cooperative drain: lane 0 reserves, all lanes store a coalesced burst
    int wid = tid >> 6, lane = tid & 63;
    for (int b = wid; b < NB1; b += P1T / 64) {
        int cnt = stg_cnt[b];
        if (cnt > SCAP) cnt = SCAP;
        if (cnt == 0) continue;                   // wave-uniform
        int gbase = 0;
        if (lane == 0) gbase = atomicAdd(&bucket_cnt[b], cnt);
        gbase = __shfl(gbase, 0, 64);
        if (lane < cnt) {
            unsigned rec = stg[b][lane];
            int gp = gbase + lane;
            if (gp < BCAP1) {
                buckets[(long long)b * BCAP1 + gp] = rec;
            } else {                               // bucket overflow (very rare)
                int sp = atomicAdd(spill_cnt, 1);
                if (sp < SPILL_CAP) {
                    spill[2 * sp]     = b * BKW + (int)(rec & (BKW - 1));
                    spill[2 * sp + 1] = (int)(rec >> 10);
                }
            }
        }
    }
}

// ---- pass 2: per coarse bucket, LDS counting sort -> global CSR ----
__global__ __launch_bounds__(1024)
void k_sort(const int* __restrict__ bucket_cnt, const unsigned* __restrict__ buckets,
            unsigned* __restrict__ srt, int* __restrict__ beg, int* __restrict__ end) {
    __shared__ int hist[BKW];                    // 4 KB
    __shared__ int scan[BKW];                    // 4 KB
    __shared__ int cursor[BKW];                  // 4 KB
    int tid = threadIdx.x;
    int b = blockIdx.x;
    int cnt = bucket_cnt[b];
    if (cnt > BCAP1) cnt = BCAP1;
    const unsigned* bk = buckets + (long long)b * BCAP1;

    hist[tid] = 0;
    __syncthreads();
    for (int k = tid; k < cnt; k += 1024) atomicAdd(&hist[bk[k] & (BKW - 1)], 1);
    __syncthreads();

    scan[tid] = hist[tid];
    __syncthreads();
    for (int d = 1; d < BKW; d <<= 1) {          // Hillis-Steele inclusive scan
        int v = (tid >= d) ? scan[tid - d] : 0;
        __syncthreads();
        if (tid >= d) scan[tid] += v;
        __syncthreads();
    }

    int base = b * BCAP1;
    int node = b * BKW + tid;
    if (node < N_NODES) {
        beg[node] = base + scan[tid] - hist[tid];
        end[node] = base + scan[tid];
    }
    cursor[tid] = 0;
    __syncthreads();

    for (int k = tid; k < cnt; k += 1024) {
        unsigned rec = bk[k];
        int d = rec & (BKW - 1);
        int pos = atomicAdd(&cursor[d], 1);
        srt[base + scan[d] - hist[d] + pos] = rec >> 10;
    }
}

// ---- pass 3: CSR gather, float4 x 16-lane rows, 4 edges per load instr ----
__global__ __launch_bounds__(256)
void k_gather(const float* __restrict__ x, const unsigned* __restrict__ srt,
              const int* __restrict__ beg, const int* __restrict__ end,
              float* __restrict__ out) {
    int tid = threadIdx.x;
    int wid = tid >> 6, lane = tid & 63;
    int sub = lane >> 4, fl = lane & 15;
    long long nb = (long long)blockIdx.x * 64;
    for (int n = wid; n < 64; n += 4) {
        long long node = nb + n;
        if (node >= N_NODES) break;              // wave-uniform
        int k0 = beg[node], k1 = end[node];
        float4 a0 = make_float4(0.f, 0.f, 0.f, 0.f);
        float4 a1 = make_float4(0.f, 0.f, 0.f, 0.f);
        int k = k0 + sub;
        for (; k + 4 < k1; k += 8) {             // 8 rows in flight per wave
            int s0 = srt[k], s1 = srt[k + 4];
            const float4 v0 = *(const float4*)&x[(long long)s0 * D_FEAT + fl * 4];
            const float4 v1 = *(const float4*)&x[(long long)s1 * D_FEAT + fl * 4];
            a0.x += v0.x; a0.y += v0.y; a0.z += v0.z; a0.w += v0.w;
            a1.x += v1.x; a1.y += v1.y; a1.z += v1.z; a1.w += v1.w;
        }
        if (k < k1) {
            int s0 = srt[k];
            const float4 v0 = *(const float4*)&x[(long long)s0 * D_FEAT + fl * 4];
            a0.x += v0.x; a0.y += v0.y; a0.z += v0.z; a0.w += v0.w;
        }
        a0.x += a1.x; a0.y += a1.y; a0.z += a1.z; a0.w += a1.w;
        a0.x += __shfl_xor(a0.x, 16, 64); a0.y += __shfl_xor(a0.y, 16, 64);
        a0.z += __shfl_xor(a0.z, 16, 64); a0.w += __shfl_xor(a0.w, 16, 64);
        a0.x += __shfl_xor(a0.x, 32, 64); a0.y += __shfl_xor(a0.y, 32, 64);
        a0.z += __shfl_xor(a0.z, 32, 64); a0.w += __shfl_xor(a0.w, 32, 64);
        if (sub == 0)
            *(float4*)&out[node * D_FEAT + fl * 4] = a0;
    }
}

// ---- pass 4: rare spilled edges via atomics (after k_gather's stores) ----
__global__ __launch_bounds__(256)
void k_spill(const float* __restrict__ x, const int* __restrict__ spill_cnt,
             const int* __restrict__ spill, float* __restrict__ out) {
    int sc = *spill_cnt;
    if (sc > SPILL_CAP) sc = SPILL_CAP;
    int total = sc * D_FEAT;
    int stride = gridDim.x * blockDim.x;
    for (int i = blockIdx.x * blockDim.x + threadIdx.x; i < total; i += stride) {
        int p = i >> 6, f = i & 63;
        int d = spill[2 * p], s = spill[2 * p + 1];
        atomicAdd(&out[(long long)d * D_FEAT + f], x[(long long)s * D_FEAT + f]);
    }
}

// fallback: direct atomic scatter
__global__ __launch_bounds__(256)
void mp_scatter_atomic(const float* __restrict__ x,
                       const int* __restrict__ src,
                       const int* __restrict__ dst,
                       float* __restrict__ out) {
    long long t = (long long)blockIdx.x * blockDim.x + threadIdx.x;
    long long e = t >> 6;
    int f = (int)(t & 63);
    if (e >= N_EDGES) return;
    atomicAdd(&out[(long long)dst[e] * D_FEAT + f],
              x[(long long)src[e] * D_FEAT + f]);
}

extern "C" void kernel_launch(void* const* d_in, const int* in_sizes, int n_in,
                              void* d_out, int out_size, void* d_ws, size_t ws_size,
                              hipStream_t stream) {
    const float* x   = (const float*)d_in[0];
    const int*   ei  = (const int*)d_in[1];   // (2, N_EDGES): row 0 = src, row 1 = dst
    const int*   src = ei;
    const int*   dst = ei + N_EDGES;
    float* out = (float*)d_out;

    // ws layout (ints):
    //   bucket_cnt[NB1] | spill_cnt[1] | spill[2*SPILL_CAP] | (align)
    //   buckets[NB1*BCAP1] | srt[NB1*BCAP1] | beg[N_NODES] | end[N_NODES]
    const size_t BK_OFF   = ((size_t)NB1 + 1 + 2 * SPILL_CAP + 63) & ~(size_t)63;
    const size_t SRT_OFF  = BK_OFF + (size_t)NB1 * BCAP1;
    const size_t BEG_OFF  = SRT_OFF + (size_t)NB1 * BCAP1;
    const size_t END_OFF  = BEG_OFF + (size_t)N_NODES;
    const size_t WS_INTS  = END_OFF + (size_t)N_NODES;
    const size_t WS_BYTES = WS_INTS * sizeof(int);   // ~11.9 MB

    if (ws_size >= WS_BYTES) {
        int*      wsi        = (int*)d_ws;
        int*      bucket_cnt = wsi;
        int*      spill_cnt  = wsi + NB1;
        int*      spill      = wsi + NB1 + 1;
        unsigned* buckets    = (unsigned*)(wsi + BK_OFF);
        unsigned* srt        = (unsigned*)(wsi + SRT_OFF);
        int*      beg        = wsi + BEG_OFF;
        int*      end        = wsi + END_OFF;

        (void)hipMemsetAsync(bucket_cnt, 0, (size_t)(NB1 + 1) * sizeof(int), stream);

        int grid_bin = (N_EDGES + CHUNK - 1) / CHUNK;     // 611
        k_bin<<<grid_bin, P1T, 0, stream>>>(src, dst, bucket_cnt, buckets,
                                            spill_cnt, spill);

        k_sort<<<NB1, 1024, 0, stream>>>(bucket_cnt, buckets, srt, beg, end);

        int grid_g = (N_NODES + 63) / 64;                 // 1563
        k_gather<<<grid_g, 256, 0, stream>>>(x, srt, beg, end, out);

        k_spill<<<32, 256, 0, stream>>>(x, spill_cnt, spill, out);
    } else {
        (void)hipMemsetAsync(out, 0, (size_t)out_size * sizeof(float), stream);
        long long total = (long long)N_EDGES * D_FEAT;
        int block = 256;
        long long grid = (total + block - 1) / block;
        mp_scatter_atomic<<<(dim3)(unsigned)grid, block, 0, stream>>>(x, src, dst, out);
    }
}

// Round 8
// 84.455 us; speedup vs baseline: 5.6712x; 5.6712x over previous
//
#include <hip/hip_runtime.h>
#include <hip/hip_bf16.h>

#define N_NODES 100000
#define N_EDGES 1250000
#define D_FEAT  64

#define BW        128                            // nodes per coarse bucket
#define NBK       ((N_NODES + BW - 1) / BW)      // 782 buckets
#define SCAP      16                             // LDS staging entries/bucket
#define CHUNK     4096                           // edges per block, pass 1
#define PASS1_T   512
#define BCAP      1792                           // global entries per bucket (mean 1600, +4.8 sigma)
#define SPILL_CAP 65536

// ---------------- pass 1: bin edges by dst bucket, LDS write-combined ----------------
// (EXACT round-5 version: measured ~28us)
// record = (src << 7) | (dst & 127)   (src < 2^17, so 24 bits total)
__global__ __launch_bounds__(PASS1_T)
void k_bin(const int* __restrict__ src, const int* __restrict__ dst,
           int* __restrict__ bucket_cnt, unsigned* __restrict__ buckets,
           int* __restrict__ spill_cnt, int* __restrict__ spill) {
    __shared__ int      stg_cnt[NBK];        // 3.1 KB
    __shared__ unsigned stg[NBK][SCAP];      // 50 KB
    int tid = threadIdx.x;
    for (int i = tid; i < NBK; i += PASS1_T) stg_cnt[i] = 0;
    __syncthreads();

    int base = blockIdx.x * CHUNK;
    #pragma unroll
    for (int r = 0; r < CHUNK / PASS1_T; ++r) {
        int e = base + r * PASS1_T + tid;
        if (e < N_EDGES) {
            int d = dst[e], s = src[e];
            int b = d >> 7;
            int pos = atomicAdd(&stg_cnt[b], 1);
            unsigned rec = ((unsigned)s << 7) | (unsigned)(d & (BW - 1));
            if (pos < SCAP) {
                stg[b][pos] = rec;
            } else {                               // staging overflow (rare)
                int sp = atomicAdd(spill_cnt, 1);
                if (sp < SPILL_CAP) { spill[2 * sp] = d; spill[2 * sp + 1] = s; }
            }
        }
    }
    __syncthreads();

    // drain: one global atomic + short contiguous burst per non-empty bucket
    for (int b = tid; b < NBK; b += PASS1_T) {
        int cnt = stg_cnt[b];
        if (cnt > SCAP) cnt = SCAP;
        if (cnt > 0) {
            int gbase = atomicAdd(&bucket_cnt[b], cnt);
            for (int k = 0; k < cnt; ++k) {
                int gp = gbase + k;
                unsigned rec = stg[b][k];
                if (gp < BCAP) {
                    buckets[(long long)b * BCAP + gp] = rec;
                } else {                           // bucket overflow (rare)
                    int sp = atomicAdd(spill_cnt, 1);
                    if (sp < SPILL_CAP) {
                        spill[2 * sp]     = b * BW + (int)(rec & (BW - 1));
                        spill[2 * sp + 1] = (int)(rec >> 7);
                    }
                }
            }
        }
    }
}

// ---------------- pass 2: per-bucket counting sort (LDS) + float4 gather ----------------
// Sort identical to round 5 (part of the measured-52us kernel). Gather loop
// upgraded: 16 lanes x float4 = one 256B row per load instr, 4 rows per wave,
// 2-way unroll, butterfly shfl reduce, float4 row store.
__global__ __launch_bounds__(512)
void k_acc(const float* __restrict__ x, const int* __restrict__ bucket_cnt,
           const unsigned* __restrict__ buckets, float* __restrict__ out) {
    __shared__ unsigned srt[BCAP];               // 7 KB: src ids sorted by dst_low
    __shared__ int hist[BW];                     // histogram, then scatter cursor
    __shared__ int offs[BW + 1];                 // start offsets per node
    __shared__ int scan_tmp[BW];
    int tid = threadIdx.x;
    int b = blockIdx.x;
    int cnt = bucket_cnt[b];
    if (cnt > BCAP) cnt = BCAP;
    const unsigned* bk = buckets + (long long)b * BCAP;

    if (tid < BW) hist[tid] = 0;
    __syncthreads();

    // histogram of dst_low (scalar LDS atomics: ~1600 per block total)
    for (int k = tid; k < cnt; k += 512) atomicAdd(&hist[bk[k] & (BW - 1)], 1);
    __syncthreads();

    // Hillis-Steele inclusive scan over 128 counters
    if (tid < BW) scan_tmp[tid] = hist[tid];
    __syncthreads();
    for (int d = 1; d < BW; d <<= 1) {
        int v = 0;
        if (tid < BW && tid >= d) v = scan_tmp[tid - d];
        __syncthreads();
        if (tid < BW && tid >= d) scan_tmp[tid] += v;
        __syncthreads();
    }
    if (tid < BW) {
        offs[tid + 1] = scan_tmp[tid];
        if (tid == 0) offs[0] = 0;
        hist[tid] = 0;                           // reuse as cursor
    }
    __syncthreads();

    // scatter records into per-node sorted order (store src id)
    for (int k = tid; k < cnt; k += 512) {
        unsigned rec = bk[k];
        int d = rec & (BW - 1);
        int pos = atomicAdd(&hist[d], 1);
        srt[offs[d] + pos] = rec >> 7;
    }
    __syncthreads();

    // one wave per node: 4 sub-groups of 16 lanes, each sub reads full 256B
    // rows via float4; 2-way unroll -> 8 rows in flight per wave.
    int wid = tid >> 6, lane = tid & 63;
    int sub = lane >> 4, fl = lane & 15;
    long long nbase = (long long)b * BW;
    for (int n = wid; n < BW; n += 8) {
        long long node = nbase + n;
        if (node >= N_NODES) break;              // wave-uniform
        int k0 = offs[n], k1 = offs[n + 1];
        float4 a0 = make_float4(0.f, 0.f, 0.f, 0.f);
        float4 a1 = make_float4(0.f, 0.f, 0.f, 0.f);
        int k = k0 + sub;
        for (; k + 4 < k1; k += 8) {
            int s0 = srt[k], s1 = srt[k + 4];
            const float4 v0 = *(const float4*)&x[(long long)s0 * D_FEAT + fl * 4];
            const float4 v1 = *(const float4*)&x[(long long)s1 * D_FEAT + fl * 4];
            a0.x += v0.x; a0.y += v0.y; a0.z += v0.z; a0.w += v0.w;
            a1.x += v1.x; a1.y += v1.y; a1.z += v1.z; a1.w += v1.w;
        }
        if (k < k1) {
            int s0 = srt[k];
            const float4 v0 = *(const float4*)&x[(long long)s0 * D_FEAT + fl * 4];
            a0.x += v0.x; a0.y += v0.y; a0.z += v0.z; a0.w += v0.w;
        }
        a0.x += a1.x; a0.y += a1.y; a0.z += a1.z; a0.w += a1.w;
        a0.x += __shfl_xor(a0.x, 16, 64); a0.y += __shfl_xor(a0.y, 16, 64);
        a0.z += __shfl_xor(a0.z, 16, 64); a0.w += __shfl_xor(a0.w, 16, 64);
        a0.x += __shfl_xor(a0.x, 32, 64); a0.y += __shfl_xor(a0.y, 32, 64);
        a0.z += __shfl_xor(a0.z, 32, 64); a0.w += __shfl_xor(a0.w, 32, 64);
        if (sub == 0)
            *(float4*)&out[node * D_FEAT + fl * 4] = a0;
    }
}

// ---------------- pass 3: rare spilled edges via atomics ----------------
__global__ __launch_bounds__(256)
void k_spill(const float* __restrict__ x, const int* __restrict__ spill_cnt,
             const int* __restrict__ spill, float* __restrict__ out) {
    int sc = *spill_cnt;
    if (sc > SPILL_CAP) sc = SPILL_CAP;
    int total = sc * D_FEAT;
    int stride = gridDim.x * blockDim.x;
    for (int i = blockIdx.x * blockDim.x + threadIdx.x; i < total; i += stride) {
        int p = i >> 6, f = i & 63;
        int d = spill[2 * p], s = spill[2 * p + 1];
        atomicAdd(&out[(long long)d * D_FEAT + f], x[(long long)s * D_FEAT + f]);
    }
}

// ---------------- fallback: direct atomic scatter ----------------
__global__ __launch_bounds__(256)
void mp_scatter_atomic(const float* __restrict__ x,
                       const int* __restrict__ src,
                       const int* __restrict__ dst,
                       float* __restrict__ out) {
    long long t = (long long)blockIdx.x * blockDim.x + threadIdx.x;
    long long e = t >> 6;
    int f = (int)(t & 63);
    if (e >= N_EDGES) return;
    atomicAdd(&out[(long long)dst[e] * D_FEAT + f],
              x[(long long)src[e] * D_FEAT + f]);
}

extern "C" void kernel_launch(void* const* d_in, const int* in_sizes, int n_in,
                              void* d_out, int out_size, void* d_ws, size_t ws_size,
                              hipStream_t stream) {
    const float* x   = (const float*)d_in[0];
    const int*   ei  = (const int*)d_in[1];   // (2, N_EDGES): row 0 = src, row 1 = dst
    const int*   src = ei;
    const int*   dst = ei + N_EDGES;
    float* out = (float*)d_out;

    // ws layout (ints): bucket_cnt[NBK] | spill_cnt[1] | spill[2*SPILL_CAP] | (align) | buckets[NBK*BCAP]
    const size_t BK_OFF   = ((size_t)NBK + 1 + 2 * SPILL_CAP + 63) & ~(size_t)63;
    const size_t WS_INTS  = BK_OFF + (size_t)NBK * BCAP;
    const size_t WS_BYTES = WS_INTS * sizeof(int);   // ~6.1 MB

    if (ws_size >= WS_BYTES) {
        int*      wsi        = (int*)d_ws;
        int*      bucket_cnt = wsi;
        int*      spill_cnt  = wsi + NBK;
        int*      spill      = wsi + NBK + 1;
        unsigned* buckets    = (unsigned*)(wsi + BK_OFF);

        (void)hipMemsetAsync(bucket_cnt, 0, (size_t)(NBK + 1) * sizeof(int), stream);

        int grid_bin = (N_EDGES + CHUNK - 1) / CHUNK;     // 306
        k_bin<<<grid_bin, PASS1_T, 0, stream>>>(src, dst, bucket_cnt, buckets,
                                                spill_cnt, spill);

        k_acc<<<NBK, 512, 0, stream>>>(x, bucket_cnt, buckets, out);

        k_spill<<<32, 256, 0, stream>>>(x, spill_cnt, spill, out);
    } else {
        (void)hipMemsetAsync(out, 0, (size_t)out_size * sizeof(float), stream);
        long long total = (long long)N_EDGES * D_FEAT;
        int block = 256;
        long long grid = (total + block - 1) / block;
        mp_scatter_atomic<<<(dim3)(unsigned)grid, block, 0, stream>>>(x, src, dst, out);
    }
}